// Round 4
// baseline (496.822 us; speedup 1.0000x reference)
//
#include <hip/hip_runtime.h>

typedef unsigned short u16;
typedef __attribute__((ext_vector_type(8))) unsigned short us8;
typedef __attribute__((ext_vector_type(8))) __bf16 bf16x8;
typedef __attribute__((ext_vector_type(4))) float floatx4;

#define B_ 2
#define S_ 2048
#define D_ 1024
#define H_ 16
#define HD_ 64

__device__ __forceinline__ float b2f(u16 u) {
  unsigned v = ((unsigned)u) << 16;
  return __builtin_bit_cast(float, v);
}
__device__ __forceinline__ u16 f2bf(float f) {
  unsigned u = __builtin_bit_cast(unsigned, f);
  unsigned r = (u + 0x7fffu + ((u >> 16) & 1u)) >> 16;
  return (u16)r;
}

// Load 8 consecutive elements starting at idx (multiple of 8) as bf16 codes.
__device__ __forceinline__ us8 load8(const void* p, size_t idx, bool f32) {
  if (f32) {
    const float* pf = (const float*)p + idx;
    floatx4 x0 = *(const floatx4*)pf;
    floatx4 x1 = *(const floatx4*)(pf + 4);
    us8 r;
#pragma unroll
    for (int i = 0; i < 4; i++) { r[i] = f2bf(x0[i]); r[4 + i] = f2bf(x1[i]); }
    return r;
  }
  return *(const us8*)((const u16*)p + idx);
}

// ---------------- GEMM: C[M,N] = A[M,K] @ B[K,N] + bias[N] -----------------
// A: fp32 (a_is_f32=1) or bf16. B, bias: fp32 (input weights). C: fp32
// (c_is_f32=1, the final output) or bf16 (intermediates). Compute: bf16 MFMA,
// fp32 accumulate. 64x64 tile, 256 threads (4 waves). B staged transposed
// into Bs[n][k] via scalar scatter; both LDS tiles XOR-swizzled per 16B chunk
// (phys_chunk = logical_chunk ^ (row & 7)).
__global__ __launch_bounds__(256) void gemm_nt(
    const void* __restrict__ A, int a_is_f32,
    const float* __restrict__ B, const float* __restrict__ bias,
    void* __restrict__ C, int c_is_f32, int M, int N, int K) {
  __shared__ __align__(16) u16 As[64 * 64];
  __shared__ __align__(16) u16 Bs[64 * 64];
  const bool af32 = (a_is_f32 != 0);
  int tid  = threadIdx.x;
  int wave = tid >> 6, lane = tid & 63;
  int quad = lane >> 4, l16 = lane & 15;
  int n0 = blockIdx.x * 64, m0 = blockIdx.y * 64;
  int sr  = tid >> 3;       // staging row 0..31 (+32 on 2nd pass)
  int sc8 = tid & 7;        // staging 8-elem chunk index
  floatx4 acc[4] = {};
  for (int k0 = 0; k0 < K; k0 += 64) {
#pragma unroll
    for (int rr = 0; rr < 2; rr++) {
      int m = sr + rr * 32;
      us8 va = load8(A, (size_t)(m0 + m) * K + k0 + sc8 * 8, af32);
      *(us8*)&As[m * 64 + ((sc8 ^ (m & 7)) << 3)] = va;
      int k = m;  // same row index used as k-row of B
      const float* bp8 = &B[(size_t)(k0 + k) * N + n0 + sc8 * 8];
      floatx4 b0 = *(const floatx4*)bp8;
      floatx4 b1 = *(const floatx4*)(bp8 + 4);
#pragma unroll
      for (int i = 0; i < 8; i++) {
        int n = sc8 * 8 + i;
        float bvf = (i < 4) ? b0[i] : b1[i - 4];
        Bs[n * 64 + (((k >> 3) ^ (n & 7)) << 3) + (k & 7)] = f2bf(bvf);
      }
    }
    __syncthreads();
    int arow = wave * 16 + l16;
#pragma unroll
    for (int kk = 0; kk < 2; kk++) {
      us8 a = *(const us8*)&As[arow * 64 + (((kk * 4 + quad) ^ (l16 & 7)) << 3)];
      bf16x8 av = __builtin_bit_cast(bf16x8, a);
#pragma unroll
      for (int nt = 0; nt < 4; nt++) {
        int nrow = nt * 16 + l16;
        us8 b = *(const us8*)&Bs[nrow * 64 + (((kk * 4 + quad) ^ (l16 & 7)) << 3)];
        acc[nt] = __builtin_amdgcn_mfma_f32_16x16x32_bf16(
            av, __builtin_bit_cast(bf16x8, b), acc[nt], 0, 0, 0);
      }
    }
    __syncthreads();
  }
#pragma unroll
  for (int nt = 0; nt < 4; nt++) {
    int col = n0 + nt * 16 + l16;
    float bv = bias[col];
#pragma unroll
    for (int r = 0; r < 4; r++) {
      int row = m0 + wave * 16 + quad * 4 + r;
      float v = acc[nt][r] + bv;
      if (c_is_f32) ((float*)C)[(size_t)row * N + col] = v;
      else          ((u16*)C)[(size_t)row * N + col] = f2bf(v);
    }
  }
}

// ---------------- Flash attention (causal), all-bf16 intermediates ---------
// Q: (B*S, 1024); KV: (B*S, 2048) with K at col h*64, V at col 1024+h*64.
// Grid (S/64, B*H), block 256. Wave w handles queries qt*64 + w*16 .. +16.
__global__ __launch_bounds__(256) void attn_fwd(
    const u16* __restrict__ Q, const u16* __restrict__ KV, u16* __restrict__ O) {
  __shared__ __align__(16) u16 Ks[64 * 64];       // K[key][hd], swizzled
  __shared__ __align__(16) u16 Vt[64 * 64];       // V^T[hd][key], swizzled
  __shared__ __align__(16) u16 Ps[4 * 16 * 64];   // per-wave P tile, swizzled
  int tid  = threadIdx.x;
  int wave = tid >> 6, lane = tid & 63;
  int quad = lane >> 4, l16 = lane & 15;
  int qt = blockIdx.x;
  int bh = blockIdx.y;
  int b = bh >> 4, h = bh & 15;
  const size_t row0 = (size_t)b * S_;

  int qrow = qt * 64 + wave * 16 + l16;
  const u16* qp = Q + (row0 + qrow) * D_ + h * HD_ + quad * 8;
  bf16x8 aqv[2];
  aqv[0] = __builtin_bit_cast(bf16x8, *(const us8*)(qp));
  aqv[1] = __builtin_bit_cast(bf16x8, *(const us8*)(qp + 32));

  float m_[4] = {-1e9f, -1e9f, -1e9f, -1e9f};
  float l_[4] = {0.f, 0.f, 0.f, 0.f};
  floatx4 o_[4] = {};

  int sr  = tid >> 3;
  int sc8 = tid & 7;
  const u16* Kg = KV + (size_t)(h * HD_);
  const u16* Vg = KV + (size_t)(D_ + h * HD_);

  for (int kb = 0; kb <= qt; kb++) {
#pragma unroll
    for (int rr = 0; rr < 2; rr++) {
      int key = sr + rr * 32;
      size_t grow = (row0 + (size_t)kb * 64 + key) * (size_t)(2 * D_);
      us8 k8 = *(const us8*)&Kg[grow + sc8 * 8];
      *(us8*)&Ks[key * 64 + ((sc8 ^ (key & 7)) << 3)] = k8;
      us8 v8 = *(const us8*)&Vg[grow + sc8 * 8];
#pragma unroll
      for (int i = 0; i < 8; i++) {
        int hd = sc8 * 8 + i;
        Vt[hd * 64 + (((key >> 3) ^ (hd & 7)) << 3) + (key & 7)] = v8[i];
      }
    }
    __syncthreads();

    // ---- S = Q K^T (per wave: 16 x 64) ----
    floatx4 s[4] = {};
#pragma unroll
    for (int kk = 0; kk < 2; kk++) {
#pragma unroll
      for (int nt = 0; nt < 4; nt++) {
        int key = nt * 16 + l16;
        us8 bfr = *(const us8*)&Ks[key * 64 + (((kk * 4 + quad) ^ (l16 & 7)) << 3)];
        s[nt] = __builtin_amdgcn_mfma_f32_16x16x32_bf16(
            aqv[kk], __builtin_bit_cast(bf16x8, bfr), s[nt], 0, 0, 0);
      }
    }

    // ---- scale + causal mask (reference: masked score = -10000) ----
    bool diag = (kb == qt);
#pragma unroll
    for (int nt = 0; nt < 4; nt++) {
#pragma unroll
      for (int r = 0; r < 4; r++) {
        float v = s[nt][r] * 0.125f;  // 1/sqrt(64)
        if (diag) {
          int qg = wave * 16 + quad * 4 + r;
          int kg = nt * 16 + l16;
          if (kg > qg) v = -10000.0f;
        }
        s[nt][r] = v;
      }
    }

    // ---- online softmax ----
    float mnew[4], alpha[4];
#pragma unroll
    for (int r = 0; r < 4; r++) {
      float rm = fmaxf(fmaxf(s[0][r], s[1][r]), fmaxf(s[2][r], s[3][r]));
      rm = fmaxf(rm, __shfl_xor(rm, 1));
      rm = fmaxf(rm, __shfl_xor(rm, 2));
      rm = fmaxf(rm, __shfl_xor(rm, 4));
      rm = fmaxf(rm, __shfl_xor(rm, 8));
      mnew[r] = fmaxf(m_[r], rm);
      alpha[r] = __expf(m_[r] - mnew[r]);
      m_[r] = mnew[r];
    }

    // ---- P = exp(S-m) -> per-wave LDS (C-layout -> A-layout) ----
#pragma unroll
    for (int nt = 0; nt < 4; nt++) {
#pragma unroll
      for (int r = 0; r < 4; r++) {
        float p = __expf(s[nt][r] - mnew[r]);
        s[nt][r] = p;
        int row = quad * 4 + r;
        int col = nt * 16 + l16;
        Ps[wave * 1024 + row * 64 + (((col >> 3) ^ (row & 7)) << 3) + (col & 7)] =
            f2bf(p);
      }
    }
#pragma unroll
    for (int r = 0; r < 4; r++) {
      float rs = s[0][r] + s[1][r] + s[2][r] + s[3][r];
      rs += __shfl_xor(rs, 1);
      rs += __shfl_xor(rs, 2);
      rs += __shfl_xor(rs, 4);
      rs += __shfl_xor(rs, 8);
      l_[r] = l_[r] * alpha[r] + rs;
      o_[0][r] *= alpha[r];
      o_[1][r] *= alpha[r];
      o_[2][r] *= alpha[r];
      o_[3][r] *= alpha[r];
    }
    __syncthreads();

    // ---- O += P V ----
#pragma unroll
    for (int kk = 0; kk < 2; kk++) {
      us8 pa = *(const us8*)&Ps[wave * 1024 + l16 * 64 +
                                (((kk * 4 + quad) ^ (l16 & 7)) << 3)];
      bf16x8 pav = __builtin_bit_cast(bf16x8, pa);
#pragma unroll
      for (int nt = 0; nt < 4; nt++) {
        int hd = nt * 16 + l16;
        us8 bv = *(const us8*)&Vt[hd * 64 + (((kk * 4 + quad) ^ (l16 & 7)) << 3)];
        o_[nt] = __builtin_amdgcn_mfma_f32_16x16x32_bf16(
            pav, __builtin_bit_cast(bf16x8, bv), o_[nt], 0, 0, 0);
      }
    }
    __syncthreads();
  }

#pragma unroll
  for (int nt = 0; nt < 4; nt++) {
    int col = h * HD_ + nt * 16 + l16;
#pragma unroll
    for (int r = 0; r < 4; r++) {
      int row = qt * 64 + wave * 16 + quad * 4 + r;
      O[(row0 + row) * D_ + col] = f2bf(o_[nt][r] / l_[r]);
    }
  }
}

extern "C" void kernel_launch(void* const* d_in, const int* in_sizes, int n_in,
                              void* d_out, int out_size, void* d_ws, size_t ws_size,
                              hipStream_t stream) {
  // Inputs are float32 (reference dtypes); output is float32.
  const void*  qf  = d_in[0];
  const void*  kvf = d_in[1];
  // d_in[2] = mask: fixed causal tril, implemented analytically (not read)
  const float* Wq  = (const float*)d_in[3];
  const float* bq  = (const float*)d_in[4];
  const float* Wkv = (const float*)d_in[5];
  const float* bkv = (const float*)d_in[6];
  const float* Wp  = (const float*)d_in[7];
  const float* bp  = (const float*)d_in[8];

  // Workspace (>= 24 MB): KVb bf16 16 MB @0, AO bf16 8 MB @16MB.
  // Qb (bf16, 8 MB) lives in d_out (16 MB of float32) — dead before the
  // final fp32 GEMM output overwrites d_out (stream-ordered).
  char* ws = (char*)d_ws;
  u16* KVb = (u16*)(ws);
  u16* AO  = (u16*)(ws + (size_t)16 * 1048576);
  u16* Qb  = (u16*)d_out;

  gemm_nt<<<dim3(16, 64), 256, 0, stream>>>(qf,  1, Wq,  bq,  Qb,  0, 4096, 1024, 1024);
  gemm_nt<<<dim3(32, 64), 256, 0, stream>>>(kvf, 1, Wkv, bkv, KVb, 0, 4096, 2048, 1024);

  attn_fwd<<<dim3(32, 32), 256, 0, stream>>>(Qb, KVb, AO);

  gemm_nt<<<dim3(16, 64), 256, 0, stream>>>(AO, 0, Wp, bp, d_out, 1, 4096, 1024, 1024);
}

// Round 5
// 338.791 us; speedup vs baseline: 1.4665x; 1.4665x over previous
//
#include <hip/hip_runtime.h>

typedef unsigned short u16;
typedef __attribute__((ext_vector_type(4))) unsigned short us4;
typedef __attribute__((ext_vector_type(8))) unsigned short us8;
typedef __attribute__((ext_vector_type(8))) __bf16 bf16x8;
typedef __attribute__((ext_vector_type(4))) float floatx4;

#define S_ 2048
#define D_ 1024

__device__ __forceinline__ float b2f(u16 u) {
  unsigned v = ((unsigned)u) << 16;
  return __builtin_bit_cast(float, v);
}
__device__ __forceinline__ u16 f2bf(float f) {
  unsigned u = __builtin_bit_cast(unsigned, f);
  unsigned r = (u + 0x7fffu + ((u >> 16) & 1u)) >> 16;
  return (u16)r;
}

// ---- weight transpose + fp32->bf16: in [R][C] f32 -> out [C][R] bf16 ------
__global__ void transpose_cvt(const float* __restrict__ in, u16* __restrict__ out,
                              int R, int C) {
  __shared__ u16 tile[32][33];
  int x = blockIdx.x * 32 + threadIdx.x;
  int y0 = blockIdx.y * 32;
  for (int i = threadIdx.y; i < 32; i += 8)
    tile[i][threadIdx.x] = f2bf(in[(size_t)(y0 + i) * C + x]);
  __syncthreads();
  int ox = y0 + threadIdx.x;
  int oy0 = blockIdx.x * 32;
  for (int i = threadIdx.y; i < 32; i += 8)
    out[(size_t)(oy0 + i) * R + ox] = tile[threadIdx.x][i];
}

// ---- GEMM: C[M,N] = A[M,K] @ Bt[N,K]^T + bias[N] --------------------------
// A: fp32 (a_f32=1) or bf16. Bt: bf16 (pre-transposed weights, k-contiguous).
// 128x128 tile, BK=64, 256 threads = 4 waves in 2x2, each wave 64x64 (4x4
// MFMA tiles). LDS XOR-swizzled at 16B chunks: phys = chunk ^ (row&7).
// mode 0: bf16 [row][N] to C0.  mode 1: fp32 [row][N] to C0.
// mode 2 (KV): col<1024 -> bf16 Kb=C0 [row][1024]; col>=1024 -> V^T to C1
//              at [(b*1024+vcol)*2048 + s] (b=row>>11, s=row&2047), us4 packed.
__global__ __launch_bounds__(256) void gemm128(
    const void* __restrict__ A, int a_f32, const u16* __restrict__ Bt,
    const float* __restrict__ bias, void* __restrict__ C0,
    u16* __restrict__ C1, int M, int N, int K, int mode) {
  __shared__ __align__(16) u16 As[128 * 64];
  __shared__ __align__(16) u16 Bs[128 * 64];
  int tid  = threadIdx.x;
  int wave = tid >> 6, lane = tid & 63;
  int quad = lane >> 4, l16 = lane & 15;
  int wr = wave >> 1, wc = wave & 1;
  int n0 = blockIdx.x * 128, m0 = blockIdx.y * 128;
  int srow = tid >> 3, sc8 = tid & 7;
  floatx4 acc[4][4] = {};

  for (int k0 = 0; k0 < K; k0 += 64) {
    if (k0) __syncthreads();
#pragma unroll
    for (int rr = 0; rr < 4; rr++) {
      int row = srow + rr * 32;
      us8 va;
      if (a_f32) {
        const float* ap = (const float*)A + (size_t)(m0 + row) * K + k0 + sc8 * 8;
        floatx4 x0 = *(const floatx4*)ap;
        floatx4 x1 = *(const floatx4*)(ap + 4);
#pragma unroll
        for (int i = 0; i < 4; i++) { va[i] = f2bf(x0[i]); va[4 + i] = f2bf(x1[i]); }
      } else {
        va = *(const us8*)((const u16*)A + (size_t)(m0 + row) * K + k0 + sc8 * 8);
      }
      *(us8*)&As[row * 64 + ((sc8 ^ (row & 7)) << 3)] = va;
      us8 vb = *(const us8*)(Bt + (size_t)(n0 + row) * K + k0 + sc8 * 8);
      *(us8*)&Bs[row * 64 + ((sc8 ^ (row & 7)) << 3)] = vb;
    }
    __syncthreads();
#pragma unroll
    for (int kk = 0; kk < 2; kk++) {
      bf16x8 af[4], bfr[4];
#pragma unroll
      for (int mt = 0; mt < 4; mt++) {
        int arow = wr * 64 + mt * 16 + l16;
        af[mt] = __builtin_bit_cast(bf16x8,
            *(const us8*)&As[arow * 64 + (((kk * 4 + quad) ^ (l16 & 7)) << 3)]);
      }
#pragma unroll
      for (int nt = 0; nt < 4; nt++) {
        int brow = wc * 64 + nt * 16 + l16;
        bfr[nt] = __builtin_bit_cast(bf16x8,
            *(const us8*)&Bs[brow * 64 + (((kk * 4 + quad) ^ (l16 & 7)) << 3)]);
      }
#pragma unroll
      for (int mt = 0; mt < 4; mt++)
#pragma unroll
        for (int nt = 0; nt < 4; nt++)
          acc[mt][nt] = __builtin_amdgcn_mfma_f32_16x16x32_bf16(
              af[mt], bfr[nt], acc[mt][nt], 0, 0, 0);
    }
  }

#pragma unroll
  for (int mt = 0; mt < 4; mt++) {
#pragma unroll
    for (int nt = 0; nt < 4; nt++) {
      int col  = n0 + wc * 64 + nt * 16 + l16;
      int rowq = m0 + wr * 64 + mt * 16 + quad * 4;
      float bv = bias[col];
      if (mode == 0) {
        u16* o = (u16*)C0;
#pragma unroll
        for (int r = 0; r < 4; r++)
          o[(size_t)(rowq + r) * N + col] = f2bf(acc[mt][nt][r] + bv);
      } else if (mode == 1) {
        float* o = (float*)C0;
#pragma unroll
        for (int r = 0; r < 4; r++)
          o[(size_t)(rowq + r) * N + col] = acc[mt][nt][r] + bv;
      } else {
        if (col < 1024) {
          u16* o = (u16*)C0;  // Kb [4096][1024]
#pragma unroll
          for (int r = 0; r < 4; r++)
            o[(size_t)(rowq + r) * 1024 + col] = f2bf(acc[mt][nt][r] + bv);
        } else {
          int vcol = col - 1024;
          int b = rowq >> 11, s0 = rowq & 2047;
          us4 pv;
#pragma unroll
          for (int r = 0; r < 4; r++) pv[r] = f2bf(acc[mt][nt][r] + bv);
          *(us4*)&C1[((size_t)(b * 1024 + vcol)) * (size_t)S_ + s0] = pv;
        }
      }
    }
  }
}

// ---- Flash attention (causal), balanced + single-barrier dbuf -------------
// Q: bf16 [token][1024]; Kb: bf16 [token][1024]; Vt: bf16 [(b*1024+h*64+hd)][2048].
// Grid (16, B*H): block x handles qt = x then qt = 31-x (33 iters, uniform).
// 256 threads = 4 waves; wave w owns 16 query rows.
__global__ __launch_bounds__(256) void attn_fwd(
    const u16* __restrict__ Q, const u16* __restrict__ Kb,
    const u16* __restrict__ Vt, u16* __restrict__ O) {
  __shared__ __align__(16) u16 Ks[2][64 * 64];   // K[key][hd], swizzled
  __shared__ __align__(16) u16 Vs[2][64 * 64];   // V^T[hd][key], swizzled
  __shared__ __align__(16) u16 Ps[4][16 * 72];   // per-wave P, pitch 72
  int tid  = threadIdx.x;
  int wave = tid >> 6, lane = tid & 63;
  int quad = lane >> 4, l16 = lane & 15;
  int bh = blockIdx.y, b = bh >> 4, h = bh & 15;
  const size_t row0 = (size_t)b * S_;
  const u16* Kg = Kb + row0 * D_ + h * 64;              // + key*1024 + hd
  const u16* Vg = Vt + ((size_t)b * 1024 + h * 64) * S_; // + hd*2048 + key
  int sr8 = tid >> 3, sc8 = tid & 7;

  for (int seg = 0; seg < 2; seg++) {
    int qt = seg ? (31 - blockIdx.x) : blockIdx.x;
    int qrow = qt * 64 + wave * 16 + l16;
    const u16* qp = Q + (row0 + qrow) * D_ + h * 64 + quad * 8;
    bf16x8 aqv[2];
    aqv[0] = __builtin_bit_cast(bf16x8, *(const us8*)(qp));
    aqv[1] = __builtin_bit_cast(bf16x8, *(const us8*)(qp + 32));

    float m_[4] = {-1e9f, -1e9f, -1e9f, -1e9f};
    float l_[4] = {0.f, 0.f, 0.f, 0.f};
    floatx4 o_[4] = {};

    __syncthreads();  // prior segment's buffer reads complete
    // stage kb=0 into buffer 0
#pragma unroll
    for (int rr = 0; rr < 2; rr++) {
      int r8 = sr8 + rr * 32;
      us8 k8 = *(const us8*)(Kg + (size_t)r8 * D_ + sc8 * 8);
      *(us8*)&Ks[0][r8 * 64 + ((sc8 ^ (r8 & 7)) << 3)] = k8;
      us8 v8 = *(const us8*)(Vg + (size_t)r8 * S_ + sc8 * 8);
      *(us8*)&Vs[0][r8 * 64 + ((sc8 ^ (r8 & 7)) << 3)] = v8;
    }

    for (int kb = 0; kb <= qt; kb++) {
      __syncthreads();  // buffer (kb&1) staged for all waves
      int cur = kb & 1;
      bool pre = kb < qt;
      us8 pk0, pk1, pv0, pv1;
      if (pre) {
        int koff = (kb + 1) * 64;
        pk0 = *(const us8*)(Kg + (size_t)(koff + sr8) * D_ + sc8 * 8);
        pk1 = *(const us8*)(Kg + (size_t)(koff + sr8 + 32) * D_ + sc8 * 8);
        pv0 = *(const us8*)(Vg + (size_t)sr8 * S_ + koff + sc8 * 8);
        pv1 = *(const us8*)(Vg + (size_t)(sr8 + 32) * S_ + koff + sc8 * 8);
      }

      // ---- S = Q K^T ----
      floatx4 s[4] = {};
#pragma unroll
      for (int kk = 0; kk < 2; kk++)
#pragma unroll
        for (int nt = 0; nt < 4; nt++) {
          int key = nt * 16 + l16;
          us8 kf = *(const us8*)&Ks[cur][key * 64 + (((kk * 4 + quad) ^ (l16 & 7)) << 3)];
          s[nt] = __builtin_amdgcn_mfma_f32_16x16x32_bf16(
              aqv[kk], __builtin_bit_cast(bf16x8, kf), s[nt], 0, 0, 0);
        }

      // ---- scale + causal mask (reference: masked score = -10000) ----
      bool diag = (kb == qt);
#pragma unroll
      for (int nt = 0; nt < 4; nt++)
#pragma unroll
        for (int r = 0; r < 4; r++) {
          float v = s[nt][r] * 0.125f;  // 1/sqrt(64)
          if (diag) {
            int qg = wave * 16 + quad * 4 + r;
            int kg = nt * 16 + l16;
            if (kg > qg) v = -10000.0f;
          }
          s[nt][r] = v;
        }

      // ---- online softmax ----
      float mnew[4], alpha[4];
#pragma unroll
      for (int r = 0; r < 4; r++) {
        float rm = fmaxf(fmaxf(s[0][r], s[1][r]), fmaxf(s[2][r], s[3][r]));
        rm = fmaxf(rm, __shfl_xor(rm, 1));
        rm = fmaxf(rm, __shfl_xor(rm, 2));
        rm = fmaxf(rm, __shfl_xor(rm, 4));
        rm = fmaxf(rm, __shfl_xor(rm, 8));
        mnew[r] = fmaxf(m_[r], rm);
        alpha[r] = __expf(m_[r] - mnew[r]);
        m_[r] = mnew[r];
      }

      // ---- P = exp(S-m) -> per-wave LDS (pitch 72, no swizzle) ----
#pragma unroll
      for (int nt = 0; nt < 4; nt++)
#pragma unroll
        for (int r = 0; r < 4; r++) {
          float p = __expf(s[nt][r] - mnew[r]);
          s[nt][r] = p;
          Ps[wave][(quad * 4 + r) * 72 + nt * 16 + l16] = f2bf(p);
        }
#pragma unroll
      for (int r = 0; r < 4; r++) {
        float rs = s[0][r] + s[1][r] + s[2][r] + s[3][r];
        rs += __shfl_xor(rs, 1);
        rs += __shfl_xor(rs, 2);
        rs += __shfl_xor(rs, 4);
        rs += __shfl_xor(rs, 8);
        l_[r] = l_[r] * alpha[r] + rs;
        o_[0][r] *= alpha[r];
        o_[1][r] *= alpha[r];
        o_[2][r] *= alpha[r];
        o_[3][r] *= alpha[r];
      }

      // ---- O += P V  (Ps is wave-private: lgkmcnt ordering suffices) ----
#pragma unroll
      for (int kk = 0; kk < 2; kk++) {
        us8 pa = *(const us8*)&Ps[wave][l16 * 72 + (kk * 4 + quad) * 8];
        bf16x8 pav = __builtin_bit_cast(bf16x8, pa);
#pragma unroll
        for (int nt = 0; nt < 4; nt++) {
          int hd = nt * 16 + l16;
          us8 vf = *(const us8*)&Vs[cur][hd * 64 + (((kk * 4 + quad) ^ (l16 & 7)) << 3)];
          o_[nt] = __builtin_amdgcn_mfma_f32_16x16x32_bf16(
              pav, __builtin_bit_cast(bf16x8, vf), o_[nt], 0, 0, 0);
        }
      }

      // ---- write prefetched kb+1 into the other buffer ----
      if (pre) {
        int nxt = cur ^ 1;
        *(us8*)&Ks[nxt][sr8 * 64 + ((sc8 ^ (sr8 & 7)) << 3)] = pk0;
        *(us8*)&Ks[nxt][(sr8 + 32) * 64 + ((sc8 ^ (sr8 & 7)) << 3)] = pk1;
        *(us8*)&Vs[nxt][sr8 * 64 + ((sc8 ^ (sr8 & 7)) << 3)] = pv0;
        *(us8*)&Vs[nxt][(sr8 + 32) * 64 + ((sc8 ^ (sr8 & 7)) << 3)] = pv1;
      }
    }

    // ---- epilogue: O / l, merged-head layout ----
#pragma unroll
    for (int nt = 0; nt < 4; nt++) {
      int col = h * 64 + nt * 16 + l16;
#pragma unroll
      for (int r = 0; r < 4; r++) {
        size_t row = row0 + qt * 64 + wave * 16 + quad * 4 + r;
        O[row * D_ + col] = f2bf(o_[nt][r] / l_[r]);
      }
    }
  }
}

extern "C" void kernel_launch(void* const* d_in, const int* in_sizes, int n_in,
                              void* d_out, int out_size, void* d_ws, size_t ws_size,
                              hipStream_t stream) {
  const float* qf  = (const float*)d_in[0];
  const float* kvf = (const float*)d_in[1];
  // d_in[2] = mask: fixed causal tril, implemented analytically (not read)
  const float* Wq  = (const float*)d_in[3];
  const float* bq  = (const float*)d_in[4];
  const float* Wkv = (const float*)d_in[5];
  const float* bkv = (const float*)d_in[6];
  const float* Wp  = (const float*)d_in[7];
  const float* bp  = (const float*)d_in[8];

  // Workspace (32 MB):
  //   Kb   bf16 [4096][1024]        8 MB @ 0
  //   Vt   bf16 [2*1024][2048]      8 MB @ 8M   (V transposed per (b,col))
  //   AO   bf16 [4096][1024]        8 MB @ 16M
  //   Wqt  bf16 [1024][1024]        2 MB @ 24M
  //   Wkvt bf16 [2048][1024]        4 MB @ 26M
  //   Wpt  bf16 [1024][1024]        2 MB @ 30M
  // Qb (bf16, 8 MB) lives in d_out (16 MB fp32), dead before final write.
  char* ws = (char*)d_ws;
  const size_t MB = 1048576;
  u16* Kbp  = (u16*)(ws);
  u16* Vtp  = (u16*)(ws + 8 * MB);
  u16* AO   = (u16*)(ws + 16 * MB);
  u16* Wqt  = (u16*)(ws + 24 * MB);
  u16* Wkvt = (u16*)(ws + 26 * MB);
  u16* Wpt  = (u16*)(ws + 30 * MB);
  u16* Qb   = (u16*)d_out;

  dim3 tb(32, 8);
  transpose_cvt<<<dim3(32, 32), tb, 0, stream>>>(Wq,  Wqt,  1024, 1024);
  transpose_cvt<<<dim3(64, 32), tb, 0, stream>>>(Wkv, Wkvt, 1024, 2048);
  transpose_cvt<<<dim3(32, 32), tb, 0, stream>>>(Wp,  Wpt,  1024, 1024);

  gemm128<<<dim3(8, 32),  256, 0, stream>>>(qf,  1, Wqt,  bq,  Qb,   nullptr,
                                            4096, 1024, 1024, 0);
  gemm128<<<dim3(16, 32), 256, 0, stream>>>(kvf, 1, Wkvt, bkv, Kbp,  Vtp,
                                            4096, 2048, 1024, 2);

  attn_fwd<<<dim3(16, 32), 256, 0, stream>>>(Qb, Kbp, Vtp, AO);

  gemm128<<<dim3(8, 32),  256, 0, stream>>>(AO, 0, Wpt, bp, d_out, nullptr,
                                            4096, 1024, 1024, 1);
}

// Round 6
// 252.736 us; speedup vs baseline: 1.9658x; 1.3405x over previous
//
#include <hip/hip_runtime.h>

typedef unsigned short u16;
typedef unsigned int u32;
typedef __attribute__((ext_vector_type(4))) unsigned short us4;
typedef __attribute__((ext_vector_type(8))) unsigned short us8;
typedef __attribute__((ext_vector_type(8))) __bf16 bf16x8;
typedef __attribute__((ext_vector_type(4))) float floatx4;

#define S_ 2048
#define D_ 1024

__device__ __forceinline__ u16 f2bf(float f) {
  unsigned u = __builtin_bit_cast(unsigned, f);
  unsigned r = (u + 0x7fffu + ((u >> 16) & 1u)) >> 16;
  return (u16)r;
}

// async global->LDS, 16B per lane; LDS dest = wave-uniform base + lane*16.
typedef const __attribute__((address_space(1))) u32* gas_t;
typedef __attribute__((address_space(3))) u32* las_t;
__device__ __forceinline__ void gload16(const u16* g, u16* l) {
  __builtin_amdgcn_global_load_lds((gas_t)g, (las_t)l, 16, 0, 0);
}

// ---- prep: fp32->bf16 convert of q/kv features + 3 weight transposes ------
// blocks 0..2047: qf cvt; 2048..4095: kvf cvt; 4096..8191: transposes.
__global__ __launch_bounds__(256) void prep(
    const float* __restrict__ qf, const float* __restrict__ kvf,
    const float* __restrict__ Wq, const float* __restrict__ Wkv,
    const float* __restrict__ Wp, u16* __restrict__ qa, u16* __restrict__ kva,
    u16* __restrict__ Wqt, u16* __restrict__ Wkvt, u16* __restrict__ Wpt) {
  int bid = blockIdx.x, tid = threadIdx.x;
  if (bid < 4096) {
    const float* src = (bid < 2048) ? qf : kvf;
    u16* dst = (bid < 2048) ? qa : kva;
    size_t i = ((size_t)(bid & 2047) * 256 + tid) * 8;
    floatx4 a = *(const floatx4*)(src + i);
    floatx4 b = *(const floatx4*)(src + i + 4);
    us8 r;
#pragma unroll
    for (int j = 0; j < 4; j++) { r[j] = f2bf(a[j]); r[4 + j] = f2bf(b[j]); }
    *(us8*)(dst + i) = r;
  } else {
    int t = bid - 4096;
    const float* src; u16* dst; int R, C;
    if (t < 1024)      { src = Wq;  dst = Wqt;  R = 1024; C = 1024; }
    else if (t < 3072) { t -= 1024; src = Wkv; dst = Wkvt; R = 1024; C = 2048; }
    else               { t -= 3072; src = Wp;  dst = Wpt;  R = 1024; C = 1024; }
    int bx = t % (C >> 5), by = t / (C >> 5);
    __shared__ u16 tile[32][33];
    int tx = tid & 31, ty = tid >> 5;
    int x = bx * 32 + tx;
    for (int i = ty; i < 32; i += 8)
      tile[i][tx] = f2bf(src[(size_t)(by * 32 + i) * C + x]);
    __syncthreads();
    int ox = by * 32 + tx;
    for (int i = ty; i < 32; i += 8)
      dst[(size_t)(bx * 32 + i) * R + ox] = tile[tx][i];
  }
}

// ---- GEMM core: C[128,128 tile] = A[M,1024] @ Bt[N,1024]^T + bias ---------
// All bf16 in, fp32 accum. m97 structure: global_load_lds(16B) staging into
// unswizzled row-major LDS, ds_read_b128 fragments, 32 MFMA / k-step.
// mode 0: bf16 out [row][N]. mode 1: fp32 out [row][N].
// mode 2 (KV): col<1024 -> bf16 Kb [row][1024]; col>=1024 -> V^T into C1 at
//              [(b*1024+(col-1024))*2048 + (row&2047)], b=row>>11.
__device__ __forceinline__ void gemm_core(
    const u16* __restrict__ A, const u16* __restrict__ Bt,
    const float* __restrict__ bias, void* __restrict__ C0,
    u16* __restrict__ C1, int N, int mode, int n0, int m0,
    u16* As, u16* Bs) {
  int tid  = threadIdx.x;
  int wave = tid >> 6, lane = tid & 63;
  int quad = lane >> 4, l16 = lane & 15;
  int wr = wave >> 1, wc = wave & 1;
  const u16* Ag = A  + (size_t)(m0 + wave * 8 + (lane >> 3)) * 1024 + (lane & 7) * 8;
  const u16* Bg = Bt + (size_t)(n0 + wave * 8 + (lane >> 3)) * 1024 + (lane & 7) * 8;
  u16* Aw = As + wave * 8 * 64;
  u16* Bw = Bs + wave * 8 * 64;
  floatx4 acc[4][4] = {};
  for (int k0 = 0; k0 < 1024; k0 += 64) {
    if (k0) __syncthreads();
#pragma unroll
    for (int p = 0; p < 4; p++) {
      gload16(Ag + (size_t)p * 32 * 1024 + k0, Aw + p * 32 * 64);
      gload16(Bg + (size_t)p * 32 * 1024 + k0, Bw + p * 32 * 64);
    }
    __syncthreads();
#pragma unroll
    for (int kk = 0; kk < 2; kk++) {
      bf16x8 af[4], bf[4];
#pragma unroll
      for (int mt = 0; mt < 4; mt++)
        af[mt] = __builtin_bit_cast(bf16x8,
            *(const us8*)&As[(wr * 64 + mt * 16 + l16) * 64 + (kk * 4 + quad) * 8]);
#pragma unroll
      for (int nt = 0; nt < 4; nt++)
        bf[nt] = __builtin_bit_cast(bf16x8,
            *(const us8*)&Bs[(wc * 64 + nt * 16 + l16) * 64 + (kk * 4 + quad) * 8]);
#pragma unroll
      for (int mt = 0; mt < 4; mt++)
#pragma unroll
        for (int nt = 0; nt < 4; nt++)
          acc[mt][nt] = __builtin_amdgcn_mfma_f32_16x16x32_bf16(
              af[mt], bf[nt], acc[mt][nt], 0, 0, 0);
    }
  }
#pragma unroll
  for (int mt = 0; mt < 4; mt++) {
#pragma unroll
    for (int nt = 0; nt < 4; nt++) {
      int col  = n0 + wc * 64 + nt * 16 + l16;
      int rowq = m0 + wr * 64 + mt * 16 + quad * 4;
      float bv = bias[col];
      if (mode == 0) {
        u16* o = (u16*)C0;
#pragma unroll
        for (int r = 0; r < 4; r++)
          o[(size_t)(rowq + r) * N + col] = f2bf(acc[mt][nt][r] + bv);
      } else if (mode == 1) {
        float* o = (float*)C0;
#pragma unroll
        for (int r = 0; r < 4; r++)
          o[(size_t)(rowq + r) * N + col] = acc[mt][nt][r] + bv;
      } else {
        if (col < 1024) {
          u16* o = (u16*)C0;
#pragma unroll
          for (int r = 0; r < 4; r++)
            o[(size_t)(rowq + r) * 1024 + col] = f2bf(acc[mt][nt][r] + bv);
        } else {
          int vcol = col - 1024;
          int b = rowq >> 11, s0 = rowq & 2047;
          us4 pv;
#pragma unroll
          for (int r = 0; r < 4; r++) pv[r] = f2bf(acc[mt][nt][r] + bv);
          *(us4*)&C1[((size_t)(b * 1024 + vcol)) * (size_t)S_ + s0] = pv;
        }
      }
    }
  }
}

// Fused Q-proj (blocks 0..255) + KV-proj (blocks 256..767).
__global__ __launch_bounds__(256) void gemm_qkv(
    const u16* __restrict__ qa, const u16* __restrict__ kva,
    const u16* __restrict__ Wqt, const u16* __restrict__ Wkvt,
    const float* __restrict__ bq, const float* __restrict__ bkv,
    u16* __restrict__ Qb, u16* __restrict__ Kb, u16* __restrict__ Vt) {
  __shared__ __align__(16) u16 As[128 * 64];
  __shared__ __align__(16) u16 Bs[128 * 64];
  int bid = blockIdx.x;
  if (bid < 256) {
    gemm_core(qa, Wqt, bq, Qb, nullptr, 1024, 0,
              (bid & 7) * 128, (bid >> 3) * 128, As, Bs);
  } else {
    int lb = bid - 256;
    gemm_core(kva, Wkvt, bkv, Kb, Vt, 2048, 2,
              (lb & 15) * 128, (lb >> 4) * 128, As, Bs);
  }
}

// Output projection: fp32 result straight into d_out.
__global__ __launch_bounds__(256) void gemm_out(
    const u16* __restrict__ AO, const u16* __restrict__ Wpt,
    const float* __restrict__ bp, float* __restrict__ out) {
  __shared__ __align__(16) u16 As[128 * 64];
  __shared__ __align__(16) u16 Bs[128 * 64];
  gemm_core(AO, Wpt, bp, out, nullptr, 1024, 1,
            (blockIdx.x & 7) * 128, (blockIdx.x >> 3) * 128, As, Bs);
}

// ---- Flash attention (causal), balanced pairing + single-barrier dbuf -----
// Grid (32 bh, 16 qpair): all q-blocks of one (b,h) land on XCD bh%8.
__global__ __launch_bounds__(256) void attn_fwd(
    const u16* __restrict__ Q, const u16* __restrict__ Kb,
    const u16* __restrict__ Vt, u16* __restrict__ O) {
  __shared__ __align__(16) u16 Ks[2][64 * 64];   // K[key][hd], swizzled
  __shared__ __align__(16) u16 Vs[2][64 * 64];   // V^T[hd][key], swizzled
  __shared__ __align__(16) u16 Ps[4][16 * 72];   // per-wave P, pitch 72
  int tid  = threadIdx.x;
  int wave = tid >> 6, lane = tid & 63;
  int quad = lane >> 4, l16 = lane & 15;
  int bh = blockIdx.x, b = bh >> 4, h = bh & 15;
  const size_t row0 = (size_t)b * S_;
  const u16* Kg = Kb + row0 * D_ + h * 64;               // + key*1024 + hd
  const u16* Vg = Vt + ((size_t)b * 1024 + h * 64) * S_; // + hd*2048 + key
  int sr8 = tid >> 3, sc8 = tid & 7;

  for (int seg = 0; seg < 2; seg++) {
    int qt = seg ? (31 - blockIdx.y) : blockIdx.y;
    int qrow = qt * 64 + wave * 16 + l16;
    const u16* qp = Q + (row0 + qrow) * D_ + h * 64 + quad * 8;
    bf16x8 aqv[2];
    aqv[0] = __builtin_bit_cast(bf16x8, *(const us8*)(qp));
    aqv[1] = __builtin_bit_cast(bf16x8, *(const us8*)(qp + 32));

    float m_[4] = {-1e9f, -1e9f, -1e9f, -1e9f};
    float l_[4] = {0.f, 0.f, 0.f, 0.f};
    floatx4 o_[4] = {};

    __syncthreads();  // prior segment's buffer reads complete
#pragma unroll
    for (int rr = 0; rr < 2; rr++) {
      int r8 = sr8 + rr * 32;
      us8 k8 = *(const us8*)(Kg + (size_t)r8 * D_ + sc8 * 8);
      *(us8*)&Ks[0][r8 * 64 + ((sc8 ^ (r8 & 7)) << 3)] = k8;
      us8 v8 = *(const us8*)(Vg + (size_t)r8 * S_ + sc8 * 8);
      *(us8*)&Vs[0][r8 * 64 + ((sc8 ^ (r8 & 7)) << 3)] = v8;
    }

    for (int kb = 0; kb <= qt; kb++) {
      __syncthreads();
      int cur = kb & 1;
      bool pre = kb < qt;
      us8 pk0, pk1, pv0, pv1;
      if (pre) {
        int koff = (kb + 1) * 64;
        pk0 = *(const us8*)(Kg + (size_t)(koff + sr8) * D_ + sc8 * 8);
        pk1 = *(const us8*)(Kg + (size_t)(koff + sr8 + 32) * D_ + sc8 * 8);
        pv0 = *(const us8*)(Vg + (size_t)sr8 * S_ + koff + sc8 * 8);
        pv1 = *(const us8*)(Vg + (size_t)(sr8 + 32) * S_ + koff + sc8 * 8);
      }

      floatx4 s[4] = {};
#pragma unroll
      for (int kk = 0; kk < 2; kk++)
#pragma unroll
        for (int nt = 0; nt < 4; nt++) {
          int key = nt * 16 + l16;
          us8 kf = *(const us8*)&Ks[cur][key * 64 + (((kk * 4 + quad) ^ (l16 & 7)) << 3)];
          s[nt] = __builtin_amdgcn_mfma_f32_16x16x32_bf16(
              aqv[kk], __builtin_bit_cast(bf16x8, kf), s[nt], 0, 0, 0);
        }

      bool diag = (kb == qt);
#pragma unroll
      for (int nt = 0; nt < 4; nt++)
#pragma unroll
        for (int r = 0; r < 4; r++) {
          float v = s[nt][r] * 0.125f;  // 1/sqrt(64)
          if (diag) {
            int qg = wave * 16 + quad * 4 + r;
            int kg = nt * 16 + l16;
            if (kg > qg) v = -10000.0f;
          }
          s[nt][r] = v;
        }

      float mnew[4], alpha[4];
#pragma unroll
      for (int r = 0; r < 4; r++) {
        float rm = fmaxf(fmaxf(s[0][r], s[1][r]), fmaxf(s[2][r], s[3][r]));
        rm = fmaxf(rm, __shfl_xor(rm, 1));
        rm = fmaxf(rm, __shfl_xor(rm, 2));
        rm = fmaxf(rm, __shfl_xor(rm, 4));
        rm = fmaxf(rm, __shfl_xor(rm, 8));
        mnew[r] = fmaxf(m_[r], rm);
        alpha[r] = __expf(m_[r] - mnew[r]);
        m_[r] = mnew[r];
      }

#pragma unroll
      for (int nt = 0; nt < 4; nt++)
#pragma unroll
        for (int r = 0; r < 4; r++) {
          float p = __expf(s[nt][r] - mnew[r]);
          s[nt][r] = p;
          Ps[wave][(quad * 4 + r) * 72 + nt * 16 + l16] = f2bf(p);
        }
#pragma unroll
      for (int r = 0; r < 4; r++) {
        float rs = s[0][r] + s[1][r] + s[2][r] + s[3][r];
        rs += __shfl_xor(rs, 1);
        rs += __shfl_xor(rs, 2);
        rs += __shfl_xor(rs, 4);
        rs += __shfl_xor(rs, 8);
        l_[r] = l_[r] * alpha[r] + rs;
        o_[0][r] *= alpha[r];
        o_[1][r] *= alpha[r];
        o_[2][r] *= alpha[r];
        o_[3][r] *= alpha[r];
      }

#pragma unroll
      for (int kk = 0; kk < 2; kk++) {
        us8 pa = *(const us8*)&Ps[wave][l16 * 72 + (kk * 4 + quad) * 8];
        bf16x8 pav = __builtin_bit_cast(bf16x8, pa);
#pragma unroll
        for (int nt = 0; nt < 4; nt++) {
          int hd = nt * 16 + l16;
          us8 vf = *(const us8*)&Vs[cur][hd * 64 + (((kk * 4 + quad) ^ (l16 & 7)) << 3)];
          o_[nt] = __builtin_amdgcn_mfma_f32_16x16x32_bf16(
              pav, __builtin_bit_cast(bf16x8, vf), o_[nt], 0, 0, 0);
        }
      }

      if (pre) {
        int nxt = cur ^ 1;
        *(us8*)&Ks[nxt][sr8 * 64 + ((sc8 ^ (sr8 & 7)) << 3)] = pk0;
        *(us8*)&Ks[nxt][(sr8 + 32) * 64 + ((sc8 ^ (sr8 & 7)) << 3)] = pk1;
        *(us8*)&Vs[nxt][sr8 * 64 + ((sc8 ^ (sr8 & 7)) << 3)] = pv0;
        *(us8*)&Vs[nxt][(sr8 + 32) * 64 + ((sc8 ^ (sr8 & 7)) << 3)] = pv1;
      }
    }

#pragma unroll
    for (int nt = 0; nt < 4; nt++) {
      int col = h * 64 + nt * 16 + l16;
#pragma unroll
      for (int r = 0; r < 4; r++) {
        size_t row = row0 + qt * 64 + wave * 16 + quad * 4 + r;
        O[row * D_ + col] = f2bf(o_[nt][r] / l_[r]);
      }
    }
  }
}

extern "C" void kernel_launch(void* const* d_in, const int* in_sizes, int n_in,
                              void* d_out, int out_size, void* d_ws, size_t ws_size,
                              hipStream_t stream) {
  const float* qf  = (const float*)d_in[0];
  const float* kvf = (const float*)d_in[1];
  // d_in[2] = mask: fixed causal tril, implemented analytically (not read)
  const float* Wq  = (const float*)d_in[3];
  const float* bq  = (const float*)d_in[4];
  const float* Wkv = (const float*)d_in[5];
  const float* bkv = (const float*)d_in[6];
  const float* Wp  = (const float*)d_in[7];
  const float* bp  = (const float*)d_in[8];

  // Workspace (exactly 32 MB, the proven size):
  //   ws+0   : kva (bf16 kv_features) then AO (attn out) — disjoint lifetimes
  //   ws+8M  : Kb  bf16 [4096][1024]
  //   ws+16M : Vt  bf16 [2*1024][2048] (V transposed per (b,col))
  //   ws+24M : Wqt 2 MB, ws+26M: Wkvt 4 MB, ws+30M: Wpt 2 MB
  // d_out (16 MB fp32): [0,8M) = qa (bf16 q_features), [8M,16M) = Qb
  // (Q-proj out). Both dead before gemm_out's fp32 write (stream-ordered).
  char* ws = (char*)d_ws;
  const size_t MB = 1048576;
  u16* kva  = (u16*)(ws);
  u16* AO   = (u16*)(ws);
  u16* Kbp  = (u16*)(ws + 8 * MB);
  u16* Vtp  = (u16*)(ws + 16 * MB);
  u16* Wqt  = (u16*)(ws + 24 * MB);
  u16* Wkvt = (u16*)(ws + 26 * MB);
  u16* Wpt  = (u16*)(ws + 30 * MB);
  u16* qa   = (u16*)d_out;
  u16* Qb   = (u16*)d_out + (size_t)4 * 1048576;

  prep<<<8192, 256, 0, stream>>>(qf, kvf, Wq, Wkv, Wp, qa, kva, Wqt, Wkvt, Wpt);
  gemm_qkv<<<768, 256, 0, stream>>>(qa, kva, Wqt, Wkvt, bq, bkv, Qb, Kbp, Vtp);
  attn_fwd<<<dim3(32, 16), 256, 0, stream>>>(Qb, Kbp, Vtp, AO);
  gemm_out<<<256, 256, 0, stream>>>(AO, Wpt, bp, (float*)d_out);
}